// Round 3
// baseline (4493.789 us; speedup 1.0000x reference)
//
#include <hip/hip_runtime.h>
#include <hip/hip_bf16.h>

// Problem constants
#define L_SEQ 1024
#define N_B   64
#define D_H   256
#define D_W   300
#define LDK   72     // padded K-tile stride (bf16 elems): 144B -> 2-way bank alias (free)
#define LDH   264    // padded 256-K stride: 528B -> 2-way (free)

typedef __bf16 bf16x8 __attribute__((ext_vector_type(8)));
typedef float  f32x4  __attribute__((ext_vector_type(4)));
typedef unsigned short us8 __attribute__((ext_vector_type(8)));

__device__ inline float b2f(unsigned short u){
    union { unsigned int i; float f; } v; v.i = ((unsigned int)u) << 16; return v.f;
}
__device__ inline unsigned short f2b(float f){
    union { float f; unsigned int i; } v; v.f = f;
    unsigned int u = v.i;
    return (unsigned short)((u + 0x7fffu + ((u >> 16) & 1u)) >> 16);
}
__device__ inline float sigf(float x){ return 1.0f / (1.0f + __expf(-x)); }
__device__ inline float tanhfast(float x){ return 1.0f - 2.0f / (__expf(2.0f*x) + 1.0f); }
__device__ inline bf16x8 as_bf(us8 x){ union { us8 u; bf16x8 b; } c; c.u = x; return c.b; }

// ---- dtype-agnostic loads: isf=1 -> fp32 data, isf=0 -> bf16 data ----
__device__ inline float ldf(const void* p, size_t i, int isf){
    return isf ? ((const float*)p)[i] : b2f(((const unsigned short*)p)[i]);
}
__device__ inline us8 ld8(const void* p, size_t i, int isf){
    if (isf){
        const float* f = (const float*)p + i;
        float4 x = *(const float4*)f;
        float4 y = *(const float4*)(f + 4);
        us8 r = { f2b(x.x), f2b(x.y), f2b(x.z), f2b(x.w),
                  f2b(y.x), f2b(y.y), f2b(y.z), f2b(y.w) };
        return r;
    }
    return *(const us8*)((const unsigned short*)p + i);
}
__device__ inline unsigned int ld2(const void* p, size_t i, int isf){
    if (isf){
        const float* f = (const float*)p + i;
        float2 x = *(const float2*)f;
        return (unsigned int)f2b(x.x) | ((unsigned int)f2b(x.y) << 16);
    }
    return *(const unsigned int*)((const unsigned short*)p + i);
}

// ---------------- dtype detector ----------------
__global__ __launch_bounds__(256) void k_detect(const void* __restrict__ h0, int* __restrict__ flag)
{
    int tid = threadIdx.x;
    const unsigned short* u = (const unsigned short*)h0;
    int cnt = 0;
    #pragma unroll
    for (int i = 0; i < 4; i++){
        unsigned short v = u[(size_t)(tid * 4 + i) * 2];
        int e = (v >> 7) & 0xFF;
        cnt += (e >= 90 && e <= 150) ? 1 : 0;
    }
    __shared__ int red[256];
    red[tid] = cnt;
    __syncthreads();
    for (int s = 128; s > 0; s >>= 1){
        if (tid < s) red[tid] += red[tid + s];
        __syncthreads();
    }
    if (tid == 0) flag[0] = (red[0] > 512) ? 0 : 1;   // majority in-window => bf16
}

// ---------------- h_hat = mean_l(h_w1) ----------------
__global__ __launch_bounds__(1024) void k_hhat(const void* __restrict__ h0,
    const int* __restrict__ slen, float* __restrict__ hhat, const int* __restrict__ flagp)
{
    int isf = flagp[0];
    int b = blockIdx.x;
    int part = threadIdx.x >> 8;
    int d = threadIdx.x & 255;
    int lenb = slen[b];
    float s = 0.f;
    for (int l = part; l < lenb; l += 4)
        s += ldf(h0, (size_t)l*16384 + b*256 + d, isf);
    __shared__ float red[1024];
    red[threadIdx.x] = s;
    __syncthreads();
    if (part == 0)
        hhat[b*256 + d] = (red[d] + red[d+256] + red[d+512] + red[d+768]) * (1.0f/1024.0f);
}

// ---------------- fg, og, sg (global-cell small gates) ----------------
__global__ __launch_bounds__(256) void k_small(const void* __restrict__ h0,
    const float* __restrict__ hhat, const void* __restrict__ Sw,
    const void* __restrict__ Su, const void* __restrict__ Sb,
    float* __restrict__ fg, float* __restrict__ og, float* __restrict__ sg,
    const int* __restrict__ flagp)
{
    int isf = flagp[0];
    int b = blockIdx.x; int d = threadIdx.x;
    __shared__ float hgl[256], hhl[256];
    hgl[d] = ldf(h0, (size_t)16777216 + b*256 + d, isf);
    hhl[d] = hhat[b*256 + d];
    __syncthreads();
    size_t sw0 = (size_t)d*256, sw1 = (size_t)(256+d)*256, sw2 = (size_t)(512+d)*256;
    size_t su0 = (size_t)d*256, su2 = (size_t)(512+d)*256;
    float a0=0.f,a1=0.f,a2=0.f,a3=0.f,a4=0.f;
    #pragma unroll 8
    for (int h=0; h<256; ++h){
        float hg = hgl[h], hh = hhl[h];
        a0 += hg * ldf(Sw, sw0+h, isf);
        a1 += hh * ldf(Su, su0+h, isf);
        a2 += hg * ldf(Sw, sw1+h, isf);
        a3 += hg * ldf(Sw, sw2+h, isf);
        a4 += hh * ldf(Su, su2+h, isf);
    }
    int i = b*256 + d;
    fg[i] = sigf(a0 + a1 + ldf(Sb, d, isf));
    sg[i] = a2 + ldf(Sb, 256 + d, isf);       // hg@Sw1 + Sb1 (for fi)
    og[i] = sigf(a3 + a4 + ldf(Sb, 512 + d, isf));
}

// ---------------- hgWvB[b][g*256+d] = hg @ Wv[g].T + Wb ----------------
__global__ __launch_bounds__(256) void k_hgwv(const void* __restrict__ h0,
    const void* __restrict__ Wv, const void* __restrict__ Wb,
    float* __restrict__ hgWvB, const int* __restrict__ flagp)
{
    int isf = flagp[0];
    int b = blockIdx.x, g = blockIdx.y, d = threadIdx.x;
    __shared__ float hgl[256];
    hgl[d] = ldf(h0, (size_t)16777216 + b*256 + d, isf);
    __syncthreads();
    size_t wv = ((size_t)g*256 + d)*256;
    float a = 0.f;
    #pragma unroll 8
    for (int h=0; h<256; ++h) a += hgl[h]*ldf(Wv, wv+h, isf);
    hgWvB[(size_t)b*1792 + g*256 + d] = a + ldf(Wb, g*256 + d, isf);
}

// ---------------- fi softmax num/den via MFMA (G = H @ Su1^T) ----------------
__global__ __launch_bounds__(256) void k_fi(const void* __restrict__ h0,
    const void* __restrict__ c0, const void* __restrict__ Su,
    const int* __restrict__ slen, const float* __restrict__ sg,
    float* __restrict__ numv, float* __restrict__ denv, const int* __restrict__ flagp)
{
    int isf = flagp[0];
    __shared__ unsigned short Hs[64*LDH];
    int tid = threadIdx.x;
    int b = blockIdx.x;
    int l0 = blockIdx.y * 64;
    int lenb = slen[b];
    #pragma unroll
    for (int i=0;i<8;i++){
        int c = tid + i*256;
        int r = c >> 5;
        int col = (c & 31) << 3;
        int l = l0 + r;
        us8 v = {0,0,0,0,0,0,0,0};
        if (l < lenb)
            v = ld8(h0, (size_t)l*16384 + b*256 + col, isf);
        *(us8*)(Hs + r*LDH + col) = v;
    }
    __syncthreads();
    int wv = tid >> 6, lane = tid & 63, qd = lane >> 4, lc = lane & 15;
    f32x4 zero4 = {0.f,0.f,0.f,0.f};
    for (int dci=0; dci<4; ++dci){
        int d = (wv*4 + dci) * 16 + lc;
        f32x4 acc[4];
        #pragma unroll
        for (int t=0;t<4;t++) acc[t] = zero4;
        #pragma unroll
        for (int ks=0; ks<8; ++ks){
            int k0 = ks*32 + qd*8;
            bf16x8 bb = as_bf(ld8(Su, (size_t)65536 + (size_t)d*256 + k0, isf));
            #pragma unroll
            for (int lt=0; lt<4; ++lt){
                bf16x8 aa = *(const bf16x8*)(Hs + (lt*16 + lc)*LDH + k0);
                acc[lt] = __builtin_amdgcn_mfma_f32_16x16x32_bf16(aa, bb, acc[lt], 0, 0, 0);
            }
        }
        float sgv = sg[b*256 + d];
        float pn = 0.f, pd = 0.f;
        #pragma unroll
        for (int lt=0; lt<4; ++lt){
            #pragma unroll
            for (int r=0; r<4; ++r){
                int l = l0 + lt*16 + qd*4 + r;
                if (l < lenb){
                    float e = __expf(sigf(acc[lt][r] + sgv));
                    pd += e;
                    pn += e * ldf(c0, (size_t)l*16384 + b*256 + d, isf);
                }
            }
        }
        pn += __shfl_xor(pn, 16); pn += __shfl_xor(pn, 32);
        pd += __shfl_xor(pd, 16); pd += __shfl_xor(pd, 32);
        if (qd == 0){
            atomicAdd(&numv[b*256 + d], pn);
            atomicAdd(&denv[b*256 + d], pd);
        }
    }
}

// ---------------- finalize global cell -> output row 1024 (fp32 out) ----------------
__global__ __launch_bounds__(256) void k_cg(const void* __restrict__ c0,
    const float* __restrict__ fg, const float* __restrict__ og,
    const float* __restrict__ numv, const float* __restrict__ denv,
    float* __restrict__ outh, float* __restrict__ outc,
    const int* __restrict__ flagp)
{
    int isf = flagp[0];
    int i = blockIdx.x*256 + threadIdx.x;
    float cg1 = ldf(c0, (size_t)16777216 + i, isf);
    float cg = fg[i]*cg1 + numv[i]/denv[i];
    float hg = og[i]*tanhfast(cg);
    outh[(size_t)16777216 + i] = hg;
    outc[(size_t)16777216 + i] = cg;
}

// ---------------- big fused GEMM + gate epilogue (fp32 out) ----------------
// C[m=(l*64+b)][n=g*256+d]; K = 5 shifted h-blocks (5*256) + src (300, padded to 320)
__global__ __launch_bounds__(256) void k_main(
    const void* __restrict__ src, const void* __restrict__ h0,
    const void* __restrict__ c0, const void* __restrict__ Ww,
    const void* __restrict__ Wu, const int* __restrict__ slen,
    const float* __restrict__ hgWvB,
    float* __restrict__ outh, float* __restrict__ outc,
    const int* __restrict__ flagp)
{
    int isf = flagp[0];
    __shared__ unsigned short As[128*LDK];
    __shared__ unsigned short Bs[112*LDK];
    int tid = threadIdx.x;
    int m0 = blockIdx.x * 128;
    int d0 = blockIdx.y * 16;
    int wv = tid >> 6, lane = tid & 63, qd = lane >> 4, lc = lane & 15;

    int ar[4], acol[4], al[4], ab[4], alen[4];
    #pragma unroll
    for (int i=0;i<4;i++){
        int c = tid + i*256;
        ar[i] = c >> 3; acol[i] = (c & 7) << 3;
        int m = m0 + ar[i];
        al[i] = m >> 6; ab[i] = m & 63;
        alen[i] = slen[ab[i]];
    }

    f32x4 zero4 = {0.f,0.f,0.f,0.f};
    f32x4 acc[2][7];
    #pragma unroll
    for (int a=0;a<2;a++)
        #pragma unroll
        for (int g=0;g<7;g++) acc[a][g] = zero4;

    for (int kt=0; kt<25; ++kt){
        __syncthreads();
        if (kt < 20){
            int j = kt >> 2;
            int koff = (kt & 3) << 6;
            #pragma unroll
            for (int i=0;i<4;i++){
                int lp = al[i] + j - 2;
                us8 v = {0,0,0,0,0,0,0,0};
                if ((unsigned)lp < 1024u && lp < alen[i])
                    v = ld8(h0, (size_t)lp*16384 + ab[i]*256 + koff + acol[i], isf);
                *(us8*)(As + ar[i]*LDK + acol[i]) = v;
            }
            #pragma unroll
            for (int i=0;i<4;i++){
                int c = tid + i*256;
                if (c < 896){
                    int rr = c >> 3, col = (c & 7) << 3;
                    int g = rr >> 4, d = d0 + (rr & 15);
                    *(us8*)(Bs + rr*LDK + col) =
                        ld8(Ww, ((size_t)g*256 + d)*1280 + j*256 + koff + col, isf);
                }
            }
        } else {
            int w0 = (kt - 20) << 6;
            #pragma unroll
            for (int i=0;i<16;i++){
                int c = tid + i*256;
                int r = c >> 5, wi = (c & 31) << 1;
                int w = w0 + wi;
                int m = m0 + r;
                unsigned int v = 0;
                if (w < 300) v = ld2(src, (size_t)m*300 + w, isf);
                *(unsigned int*)(As + r*LDK + wi) = v;
            }
            #pragma unroll
            for (int i=0;i<14;i++){
                int c = tid + i*256;
                int rr = c >> 5, wi = (c & 31) << 1;
                int w = w0 + wi;
                int g = rr >> 4, d = d0 + (rr & 15);
                unsigned int v = 0;
                if (w < 300) v = ld2(Wu, ((size_t)g*256 + d)*300 + w, isf);
                *(unsigned int*)(Bs + rr*LDK + wi) = v;
            }
        }
        __syncthreads();
        #pragma unroll
        for (int ks=0; ks<2; ++ks){
            int k0 = (ks << 5) + (qd << 3);
            bf16x8 a0 = *(const bf16x8*)(As + (wv*32 + lc)*LDK + k0);
            bf16x8 a1 = *(const bf16x8*)(As + (wv*32 + 16 + lc)*LDK + k0);
            #pragma unroll
            for (int g=0; g<7; ++g){
                bf16x8 bg = *(const bf16x8*)(Bs + (g*16 + lc)*LDK + k0);
                acc[0][g] = __builtin_amdgcn_mfma_f32_16x16x32_bf16(a0, bg, acc[0][g], 0,0,0);
                acc[1][g] = __builtin_amdgcn_mfma_f32_16x16x32_bf16(a1, bg, acc[1][g], 0,0,0);
            }
        }
    }

    // Fused gate epilogue
    int d = d0 + lc;
    #pragma unroll
    for (int mt=0; mt<2; ++mt){
        #pragma unroll
        for (int r=0; r<4; ++r){
            int m = m0 + wv*32 + mt*16 + qd*4 + r;
            int l = m >> 6, b = m & 63;
            size_t oi = (size_t)m*256 + d;
            int lenb = slen[b];
            float hw = 0.f, cw = 0.f;
            if (l < lenb){
                const float* hv = hgWvB + (size_t)b*1792 + d;
                float p0 = acc[mt][0][r] + hv[0];      // i_
                float p1 = acc[mt][1][r] + hv[256];    // l_
                float p2 = acc[mt][2][r] + hv[512];    // r_
                float p3 = acc[mt][3][r] + hv[768];    // f_
                float p4 = acc[mt][4][r] + hv[1024];   // s_
                float p5 = acc[mt][5][r] + hv[1280];   // o_
                float p6 = acc[mt][6][r] + hv[1536];   // u_
                float e_l = __expf(sigf(p1));
                float e_f = __expf(sigf(p3));
                float e_r = __expf(sigf(p2));
                float e_s = __expf(sigf(p4));
                float e_i = __expf(sigf(p0));
                float S = e_l + e_f + e_r + e_s + e_i;
                float u_ = tanhfast(p6);
                float cl = (l >= 1) ? ldf(c0, oi - 16384, isf) : 0.f;
                float cc = ldf(c0, oi, isf);
                float cr = (l + 1 < lenb) ? ldf(c0, oi + 16384, isf) : 0.f;
                float cg1 = ldf(c0, (size_t)16777216 + b*256 + d, isf);
                cw = (e_l*cl + e_f*cc + e_r*cr + e_s*cg1 + e_i*u_) / S;
                hw = sigf(p5) * tanhfast(cw);
            }
            outh[oi] = hw;
            outc[oi] = cw;
        }
    }
}

extern "C" void kernel_launch(void* const* d_in, const int* in_sizes, int n_in,
                              void* d_out, int out_size, void* d_ws, size_t ws_size,
                              hipStream_t stream)
{
    const void* src = d_in[0];
    const void* h0  = d_in[1];
    const void* c0  = d_in[2];
    const void* Ww  = d_in[3];
    const void* Wu  = d_in[4];
    const void* Wv  = d_in[5];
    const void* Wb  = d_in[6];
    const void* Sw  = d_in[7];
    const void* Su  = d_in[8];
    const void* Sb  = d_in[9];
    const int* slen = (const int*)d_in[10];

    float* outh = (float*)d_out;
    float* outc = outh + (size_t)1025*64*256;

    float* ws    = (float*)d_ws;
    float* hhat  = ws;
    float* fg    = ws + 16384;
    float* og    = ws + 32768;
    float* sg    = ws + 49152;
    float* numv  = ws + 65536;
    float* denv  = ws + 81920;
    float* hgWvB = ws + 98304;            // 64*1792 floats
    int*   flag  = (int*)(ws + 212992);   // 1 int

    hipLaunchKernelGGL(k_detect, dim3(1), dim3(256), 0, stream, h0, flag);
    hipMemsetAsync(numv, 0, (size_t)2*16384*sizeof(float), stream);
    hipLaunchKernelGGL(k_hhat, dim3(64), dim3(1024), 0, stream, h0, slen, hhat, flag);
    hipLaunchKernelGGL(k_small, dim3(64), dim3(256), 0, stream, h0, hhat, Sw, Su, Sb, fg, og, sg, flag);
    hipLaunchKernelGGL(k_hgwv, dim3(64,7), dim3(256), 0, stream, h0, Wv, Wb, hgWvB, flag);
    hipLaunchKernelGGL(k_fi, dim3(64,16), dim3(256), 0, stream, h0, c0, Su, slen, sg, numv, denv, flag);
    hipLaunchKernelGGL(k_cg, dim3(64), dim3(256), 0, stream, c0, fg, og, numv, denv, outh, outc, flag);
    hipLaunchKernelGGL(k_main, dim3(512,16), dim3(256), 0, stream,
                       src, h0, c0, Ww, Wu, slen, hgWvB, outh, outc, flag);
}

// Round 4
// 1079.259 us; speedup vs baseline: 4.1638x; 4.1638x over previous
//
#include <hip/hip_runtime.h>
#include <hip/hip_bf16.h>

// Problem constants
#define L_SEQ 1024
#define N_B   64
#define D_H   256
#define D_W   300
#define LDK   72     // slow-path padded K-tile stride
#define LDH   264    // padded 256-K stride: 528B -> 2-way (free)

typedef __bf16 bf16x8 __attribute__((ext_vector_type(8)));
typedef float  f32x4  __attribute__((ext_vector_type(4)));
typedef unsigned short us8 __attribute__((ext_vector_type(8)));

#if defined(__has_builtin)
#if __has_builtin(__builtin_amdgcn_global_load_lds)
#define HAS_ASYNC_LDS 1
#endif
#endif

__device__ inline float b2f(unsigned short u){
    union { unsigned int i; float f; } v; v.i = ((unsigned int)u) << 16; return v.f;
}
__device__ inline unsigned short f2b(float f){
    union { float f; unsigned int i; } v; v.f = f;
    unsigned int u = v.i;
    return (unsigned short)((u + 0x7fffu + ((u >> 16) & 1u)) >> 16);
}
__device__ inline float sigf(float x){ return 1.0f / (1.0f + __expf(-x)); }
__device__ inline float tanhfast(float x){ return 1.0f - 2.0f / (__expf(2.0f*x) + 1.0f); }

// ---- dtype-agnostic loads: isf=1 -> fp32 data, isf=0 -> bf16 data ----
__device__ inline float ldf(const void* p, size_t i, int isf){
    return isf ? ((const float*)p)[i] : b2f(((const unsigned short*)p)[i]);
}
__device__ inline unsigned short ld1b(const void* p, size_t i, int isf){
    return isf ? f2b(((const float*)p)[i]) : ((const unsigned short*)p)[i];
}
__device__ inline us8 ld8(const void* p, size_t i, int isf){
    if (isf){
        const float* f = (const float*)p + i;
        float4 x = *(const float4*)f;
        float4 y = *(const float4*)(f + 4);
        us8 r = { f2b(x.x), f2b(x.y), f2b(x.z), f2b(x.w),
                  f2b(y.x), f2b(y.y), f2b(y.z), f2b(y.w) };
        return r;
    }
    return *(const us8*)((const unsigned short*)p + i);
}
__device__ inline unsigned int ld2(const void* p, size_t i, int isf){
    if (isf){
        const float* f = (const float*)p + i;
        float2 x = *(const float2*)f;
        return (unsigned int)f2b(x.x) | ((unsigned int)f2b(x.y) << 16);
    }
    return *(const unsigned int*)((const unsigned short*)p + i);
}

// async 16B/lane global->LDS; lds_base must be wave-uniform (HW adds lane*16)
__device__ inline void stage16(const unsigned short* g, unsigned short* lds_base, int lane){
#ifdef HAS_ASYNC_LDS
    __builtin_amdgcn_global_load_lds(
        (const __attribute__((address_space(1))) unsigned int*)g,
        (__attribute__((address_space(3))) unsigned int*)lds_base, 16, 0, 0);
#else
    *(us8*)(lds_base + lane*8) = *(const us8*)g;
#endif
}

// ---------------- dtype detector ----------------
__global__ __launch_bounds__(256) void k_detect(const void* __restrict__ h0, int* __restrict__ flag)
{
    int tid = threadIdx.x;
    const unsigned short* u = (const unsigned short*)h0;
    int cnt = 0;
    #pragma unroll
    for (int i = 0; i < 4; i++){
        unsigned short v = u[(size_t)(tid * 4 + i) * 2];
        int e = (v >> 7) & 0xFF;
        cnt += (e >= 90 && e <= 150) ? 1 : 0;
    }
    __shared__ int red[256];
    red[tid] = cnt;
    __syncthreads();
    for (int s = 128; s > 0; s >>= 1){
        if (tid < s) red[tid] += red[tid + s];
        __syncthreads();
    }
    if (tid == 0) flag[0] = (red[0] > 512) ? 0 : 1;
}

// ================= conversion kernels (fast path) =================
// hpad[i][b][d], i in [0,1028): i-2 = l; rows 0,1,1026,1027 zero; masked by slen.
__global__ __launch_bounds__(256) void k_conv_h(const void* __restrict__ h0,
    const int* __restrict__ slen, unsigned short* __restrict__ hpad, const int* __restrict__ flagp)
{
    int isf = flagp[0];
    int i = blockIdx.y;
    int idx = (blockIdx.x*256 + threadIdx.x)*8;
    int b = idx >> 8;
    int l = i - 2;
    us8 v = {0,0,0,0,0,0,0,0};
    if ((unsigned)l < 1024u && l < slen[b])
        v = ld8(h0, (size_t)l*16384 + idx, isf);
    *(us8*)(hpad + (size_t)i*16384 + idx) = v;
}

// srcpad[m][320], cols 300..320 zero
__global__ __launch_bounds__(256) void k_conv_src(const void* __restrict__ src,
    unsigned short* __restrict__ srcpad, const int* __restrict__ flagp)
{
    int isf = flagp[0];
    int gid = blockIdx.x*256 + threadIdx.x;   // < 65536*40
    int row = gid / 40, k = gid % 40, col = k*8;
    us8 v = {0,0,0,0,0,0,0,0};
    if (col + 8 <= 300) v = ld8(src, (size_t)row*300 + col, isf);
    else if (col < 300){
        for (int e = 0; e < 300 - col; ++e) v[e] = ld1b(src, (size_t)row*300 + col + e, isf);
    }
    *(us8*)(srcpad + (size_t)row*320 + col) = v;
}

// Wcat[row'][1600] where row' = (d>>4)*112 + g*16 + (d&15); cols 0..1280=Ww, 1280..1600=Wu pad
__global__ __launch_bounds__(256) void k_conv_w(const void* __restrict__ Ww,
    const void* __restrict__ Wu, unsigned short* __restrict__ Wcat, const int* __restrict__ flagp)
{
    int isf = flagp[0];
    int gid = blockIdx.x*256 + threadIdx.x;   // < 1792*200
    int row = gid / 200, k = gid % 200, col = k*8;
    int dgrp = row / 112, rem = row % 112;
    int g = rem >> 4, d = dgrp*16 + (rem & 15);
    size_t n = (size_t)g*256 + d;
    us8 v = {0,0,0,0,0,0,0,0};
    if (col < 1280) v = ld8(Ww, n*1280 + col, isf);
    else {
        int w = col - 1280;
        if (w + 8 <= 300) v = ld8(Wu, n*300 + w, isf);
        else if (w < 300){
            for (int e = 0; e < 300 - w; ++e) v[e] = ld1b(Wu, n*300 + w + e, isf);
        }
    }
    *(us8*)(Wcat + (size_t)row*1600 + col) = v;
}

__global__ __launch_bounds__(256) void k_conv_su(const void* __restrict__ Su,
    unsigned short* __restrict__ Subf, const int* __restrict__ flagp)
{
    int isf = flagp[0];
    int gid = blockIdx.x*256 + threadIdx.x;
    *(us8*)(Subf + (size_t)gid*8) = ld8(Su, (size_t)65536 + (size_t)gid*8, isf);
}

// ---------------- h_hat partial sums from hpad (fast) ----------------
__global__ __launch_bounds__(256) void k_hhat_fast(const unsigned short* __restrict__ hpad,
    float* __restrict__ hhat)
{
    int b = blockIdx.x, part = blockIdx.y, d = threadIdx.x;
    float s = 0.f;
    const unsigned short* p = hpad + (size_t)(2 + part*128)*16384 + b*256 + d;
    for (int ll = 0; ll < 128; ++ll)
        s += b2f(p[(size_t)ll*16384]);
    atomicAdd(&hhat[b*256 + d], s);
}

// ---------------- h_hat (slow path) ----------------
__global__ __launch_bounds__(1024) void k_hhat(const void* __restrict__ h0,
    const int* __restrict__ slen, float* __restrict__ hhat, const int* __restrict__ flagp)
{
    int isf = flagp[0];
    int b = blockIdx.x;
    int part = threadIdx.x >> 8;
    int d = threadIdx.x & 255;
    int lenb = slen[b];
    float s = 0.f;
    for (int l = part; l < lenb; l += 4)
        s += ldf(h0, (size_t)l*16384 + b*256 + d, isf);
    __shared__ float red[1024];
    red[threadIdx.x] = s;
    __syncthreads();
    if (part == 0)
        hhat[b*256 + d] = (red[d] + red[d+256] + red[d+512] + red[d+768]);
}

// ---------------- fg, og, sg (global-cell small gates) ----------------
__global__ __launch_bounds__(256) void k_small(const void* __restrict__ h0,
    const float* __restrict__ hhat, const void* __restrict__ Sw,
    const void* __restrict__ Su, const void* __restrict__ Sb,
    float* __restrict__ fg, float* __restrict__ og, float* __restrict__ sg,
    const int* __restrict__ flagp, float hs)
{
    int isf = flagp[0];
    int b = blockIdx.x; int d = threadIdx.x;
    __shared__ float hgl[256], hhl[256];
    hgl[d] = ldf(h0, (size_t)16777216 + b*256 + d, isf);
    hhl[d] = hhat[b*256 + d] * hs;
    __syncthreads();
    size_t sw0 = (size_t)d*256, sw1 = (size_t)(256+d)*256, sw2 = (size_t)(512+d)*256;
    size_t su0 = (size_t)d*256, su2 = (size_t)(512+d)*256;
    float a0=0.f,a1=0.f,a2=0.f,a3=0.f,a4=0.f;
    #pragma unroll 8
    for (int h=0; h<256; ++h){
        float hg = hgl[h], hh = hhl[h];
        a0 += hg * ldf(Sw, sw0+h, isf);
        a1 += hh * ldf(Su, su0+h, isf);
        a2 += hg * ldf(Sw, sw1+h, isf);
        a3 += hg * ldf(Sw, sw2+h, isf);
        a4 += hh * ldf(Su, su2+h, isf);
    }
    int i = b*256 + d;
    fg[i] = sigf(a0 + a1 + ldf(Sb, d, isf));
    sg[i] = a2 + ldf(Sb, 256 + d, isf);
    og[i] = sigf(a3 + a4 + ldf(Sb, 512 + d, isf));
}

// ---------------- hgWvB[b][g*256+d] = hg @ Wv[g].T + Wb ----------------
__global__ __launch_bounds__(256) void k_hgwv(const void* __restrict__ h0,
    const void* __restrict__ Wv, const void* __restrict__ Wb,
    float* __restrict__ hgWvB, const int* __restrict__ flagp)
{
    int isf = flagp[0];
    int b = blockIdx.x, g = blockIdx.y, d = threadIdx.x;
    __shared__ float hgl[256];
    hgl[d] = ldf(h0, (size_t)16777216 + b*256 + d, isf);
    __syncthreads();
    size_t wv = ((size_t)g*256 + d)*256;
    float a = 0.f;
    #pragma unroll 8
    for (int h=0; h<256; ++h) a += hgl[h]*ldf(Wv, wv+h, isf);
    hgWvB[(size_t)b*1792 + g*256 + d] = a + ldf(Wb, g*256 + d, isf);
}

// ---------------- fi softmax num/den via MFMA — fast (bf16 hpad/Subf) ----------------
__global__ __launch_bounds__(256) void k_fi_fast(const unsigned short* __restrict__ hpad,
    const void* __restrict__ c0, const unsigned short* __restrict__ Subf,
    const int* __restrict__ slen, const float* __restrict__ sg,
    float* __restrict__ numv, float* __restrict__ denv, const int* __restrict__ flagp)
{
    int isf = flagp[0];
    __shared__ unsigned short Hs[64*LDH];
    int tid = threadIdx.x;
    int b = blockIdx.x;
    int l0 = blockIdx.y * 64;
    int lenb = slen[b];
    #pragma unroll
    for (int i=0;i<8;i++){
        int c = tid + i*256;
        int r = c >> 5;
        int col = (c & 31) << 3;
        *(us8*)(Hs + r*LDH + col) =
            *(const us8*)(hpad + (size_t)(l0 + r + 2)*16384 + b*256 + col);
    }
    __syncthreads();
    int wv = tid >> 6, lane = tid & 63, qd = lane >> 4, lc = lane & 15;
    f32x4 zero4 = {0.f,0.f,0.f,0.f};
    for (int dci=0; dci<4; ++dci){
        int d = (wv*4 + dci) * 16 + lc;
        f32x4 acc[4];
        #pragma unroll
        for (int t=0;t<4;t++) acc[t] = zero4;
        #pragma unroll
        for (int ks=0; ks<8; ++ks){
            int k0 = ks*32 + qd*8;
            bf16x8 bb = *(const bf16x8*)(Subf + (size_t)d*256 + k0);
            #pragma unroll
            for (int lt=0; lt<4; ++lt){
                bf16x8 aa = *(const bf16x8*)(Hs + (lt*16 + lc)*LDH + k0);
                acc[lt] = __builtin_amdgcn_mfma_f32_16x16x32_bf16(aa, bb, acc[lt], 0, 0, 0);
            }
        }
        float sgv = sg[b*256 + d];
        float pn = 0.f, pd = 0.f;
        #pragma unroll
        for (int lt=0; lt<4; ++lt){
            #pragma unroll
            for (int r=0; r<4; ++r){
                int l = l0 + lt*16 + qd*4 + r;
                if (l < lenb){
                    float e = __expf(sigf(acc[lt][r] + sgv));
                    pd += e;
                    pn += e * ldf(c0, (size_t)l*16384 + b*256 + d, isf);
                }
            }
        }
        pn += __shfl_xor(pn, 16); pn += __shfl_xor(pn, 32);
        pd += __shfl_xor(pd, 16); pd += __shfl_xor(pd, 32);
        if (qd == 0){
            atomicAdd(&numv[b*256 + d], pn);
            atomicAdd(&denv[b*256 + d], pd);
        }
    }
}

// ---------------- fi (slow path, raw inputs) ----------------
__global__ __launch_bounds__(256) void k_fi(const void* __restrict__ h0,
    const void* __restrict__ c0, const void* __restrict__ Su,
    const int* __restrict__ slen, const float* __restrict__ sg,
    float* __restrict__ numv, float* __restrict__ denv, const int* __restrict__ flagp)
{
    int isf = flagp[0];
    __shared__ unsigned short Hs[64*LDH];
    int tid = threadIdx.x;
    int b = blockIdx.x;
    int l0 = blockIdx.y * 64;
    int lenb = slen[b];
    #pragma unroll
    for (int i=0;i<8;i++){
        int c = tid + i*256;
        int r = c >> 5;
        int col = (c & 31) << 3;
        int l = l0 + r;
        us8 v = {0,0,0,0,0,0,0,0};
        if (l < lenb)
            v = ld8(h0, (size_t)l*16384 + b*256 + col, isf);
        *(us8*)(Hs + r*LDH + col) = v;
    }
    __syncthreads();
    int wv = tid >> 6, lane = tid & 63, qd = lane >> 4, lc = lane & 15;
    f32x4 zero4 = {0.f,0.f,0.f,0.f};
    for (int dci=0; dci<4; ++dci){
        int d = (wv*4 + dci) * 16 + lc;
        f32x4 acc[4];
        #pragma unroll
        for (int t=0;t<4;t++) acc[t] = zero4;
        #pragma unroll
        for (int ks=0; ks<8; ++ks){
            int k0 = ks*32 + qd*8;
            union { us8 u; bf16x8 b; } cv; cv.u = ld8(Su, (size_t)65536 + (size_t)d*256 + k0, isf);
            bf16x8 bb = cv.b;
            #pragma unroll
            for (int lt=0; lt<4; ++lt){
                bf16x8 aa = *(const bf16x8*)(Hs + (lt*16 + lc)*LDH + k0);
                acc[lt] = __builtin_amdgcn_mfma_f32_16x16x32_bf16(aa, bb, acc[lt], 0, 0, 0);
            }
        }
        float sgv = sg[b*256 + d];
        float pn = 0.f, pd = 0.f;
        #pragma unroll
        for (int lt=0; lt<4; ++lt){
            #pragma unroll
            for (int r=0; r<4; ++r){
                int l = l0 + lt*16 + qd*4 + r;
                if (l < lenb){
                    float e = __expf(sigf(acc[lt][r] + sgv));
                    pd += e;
                    pn += e * ldf(c0, (size_t)l*16384 + b*256 + d, isf);
                }
            }
        }
        pn += __shfl_xor(pn, 16); pn += __shfl_xor(pn, 32);
        pd += __shfl_xor(pd, 16); pd += __shfl_xor(pd, 32);
        if (qd == 0){
            atomicAdd(&numv[b*256 + d], pn);
            atomicAdd(&denv[b*256 + d], pd);
        }
    }
}

// ---------------- finalize global cell ----------------
__global__ __launch_bounds__(256) void k_cg(const void* __restrict__ c0,
    const float* __restrict__ fg, const float* __restrict__ og,
    const float* __restrict__ numv, const float* __restrict__ denv,
    float* __restrict__ outh, float* __restrict__ outc,
    const int* __restrict__ flagp)
{
    int isf = flagp[0];
    int i = blockIdx.x*256 + threadIdx.x;
    float cg1 = ldf(c0, (size_t)16777216 + i, isf);
    float cg = fg[i]*cg1 + numv[i]/denv[i];
    float hg = og[i]*tanhfast(cg);
    outh[(size_t)16777216 + i] = hg;
    outc[(size_t)16777216 + i] = cg;
}

// ================= fast main GEMM: async staging, uniform 25 stages =================
// grid (16, 512): bx = d-tile (d0 = bx*16), by = m-tile (m0 = by*128)
__global__ __launch_bounds__(256) void k_main_fast(
    const unsigned short* __restrict__ hpad, const unsigned short* __restrict__ srcpad,
    const unsigned short* __restrict__ Wcat, const void* __restrict__ c0,
    const int* __restrict__ slen, const float* __restrict__ hgWvB,
    float* __restrict__ outh, float* __restrict__ outc, const int* __restrict__ flagp)
{
    int isf = flagp[0];
    __shared__ unsigned short As[128*64];
    __shared__ unsigned short Bs[112*64];
    int tid = threadIdx.x;
    int d0 = blockIdx.x * 16;
    int m0 = blockIdx.y * 128;
    int wv = tid >> 6, lane = tid & 63, qd = lane >> 4, lc = lane & 15;

    const unsigned short* gbB = Wcat + (size_t)blockIdx.x * 112 * 1600;

    // slot -> (row, swizzled global chunk) for issues 0..3 (s = i*256+tid)
    int arow[4], agc[4];
    #pragma unroll
    for (int i=0;i<4;i++){
        int s = i*256 + tid;
        arow[i] = s >> 3;
        agc[i]  = ((s & 7) ^ ((s >> 3) & 7)) << 3;
    }
    int s3 = 768 + tid;                       // B 4th (partial) issue, tid<128
    int brow3 = s3 >> 3;
    int bgc3  = ((s3 & 7) ^ ((s3 >> 3) & 7)) << 3;

    f32x4 zero4 = {0.f,0.f,0.f,0.f};
    f32x4 acc[2][7];
    #pragma unroll
    for (int a=0;a<2;a++)
        #pragma unroll
        for (int g=0;g<7;g++) acc[a][g] = zero4;

    for (int kt=0; kt<25; ++kt){
        __syncthreads();
        const unsigned short* ga; int astr;
        if (kt < 20){
            ga = hpad + (((size_t)(m0 + ((kt>>2)<<6))) << 8) + ((kt & 3) << 6);
            astr = 256;
        } else {
            ga = srcpad + (size_t)m0*320 + ((kt - 20) << 6);
            astr = 320;
        }
        #pragma unroll
        for (int i=0;i<4;i++)
            stage16(ga + (size_t)arow[i]*astr + agc[i], As + i*2048 + wv*512, lane);
        const unsigned short* gb = gbB + ((size_t)kt << 6);
        #pragma unroll
        for (int i=0;i<3;i++)
            stage16(gb + (size_t)arow[i]*1600 + agc[i], Bs + i*2048 + wv*512, lane);
        if (tid < 128)
            stage16(gb + (size_t)brow3*1600 + bgc3, Bs + 3*2048 + wv*512, lane);
        __syncthreads();
        #pragma unroll
        for (int ks=0; ks<2; ++ks){
            int ch = (ks << 2) + qd;
            int xa = (ch ^ (lc & 7)) << 3;
            bf16x8 a0 = *(const bf16x8*)(As + (wv*32 + lc)*64 + xa);
            bf16x8 a1 = *(const bf16x8*)(As + (wv*32 + 16 + lc)*64 + xa);
            #pragma unroll
            for (int g=0; g<7; ++g){
                bf16x8 bg = *(const bf16x8*)(Bs + (g*16 + lc)*64 + xa);
                acc[0][g] = __builtin_amdgcn_mfma_f32_16x16x32_bf16(a0, bg, acc[0][g], 0,0,0);
                acc[1][g] = __builtin_amdgcn_mfma_f32_16x16x32_bf16(a1, bg, acc[1][g], 0,0,0);
            }
        }
    }

    // Fused gate epilogue
    int d = d0 + lc;
    #pragma unroll
    for (int mt=0; mt<2; ++mt){
        #pragma unroll
        for (int r=0; r<4; ++r){
            int m = m0 + wv*32 + mt*16 + qd*4 + r;
            int l = m >> 6, b = m & 63;
            size_t oi = (size_t)m*256 + d;
            int lenb = slen[b];
            float hw = 0.f, cw = 0.f;
            if (l < lenb){
                const float* hv = hgWvB + (size_t)b*1792 + d;
                float p0 = acc[mt][0][r] + hv[0];
                float p1 = acc[mt][1][r] + hv[256];
                float p2 = acc[mt][2][r] + hv[512];
                float p3 = acc[mt][3][r] + hv[768];
                float p4 = acc[mt][4][r] + hv[1024];
                float p5 = acc[mt][5][r] + hv[1280];
                float p6 = acc[mt][6][r] + hv[1536];
                float e_l = __expf(sigf(p1));
                float e_f = __expf(sigf(p3));
                float e_r = __expf(sigf(p2));
                float e_s = __expf(sigf(p4));
                float e_i = __expf(sigf(p0));
                float S = e_l + e_f + e_r + e_s + e_i;
                float u_ = tanhfast(p6);
                float cl = (l >= 1) ? ldf(c0, oi - 16384, isf) : 0.f;
                float cc = ldf(c0, oi, isf);
                float cr = (l + 1 < lenb) ? ldf(c0, oi + 16384, isf) : 0.f;
                float cg1 = ldf(c0, (size_t)16777216 + b*256 + d, isf);
                cw = (e_l*cl + e_f*cc + e_r*cr + e_s*cg1 + e_i*u_) / S;
                hw = sigf(p5) * tanhfast(cw);
            }
            outh[oi] = hw;
            outc[oi] = cw;
        }
    }
}

// ================= slow main GEMM (fallback, raw inputs) =================
__global__ __launch_bounds__(256) void k_main(
    const void* __restrict__ src, const void* __restrict__ h0,
    const void* __restrict__ c0, const void* __restrict__ Ww,
    const void* __restrict__ Wu, const int* __restrict__ slen,
    const float* __restrict__ hgWvB,
    float* __restrict__ outh, float* __restrict__ outc,
    const int* __restrict__ flagp)
{
    int isf = flagp[0];
    __shared__ unsigned short As[128*LDK];
    __shared__ unsigned short Bs[112*LDK];
    int tid = threadIdx.x;
    int m0 = blockIdx.x * 128;
    int d0 = blockIdx.y * 16;
    int wv = tid >> 6, lane = tid & 63, qd = lane >> 4, lc = lane & 15;

    int ar[4], acol[4], al[4], ab[4], alen[4];
    #pragma unroll
    for (int i=0;i<4;i++){
        int c = tid + i*256;
        ar[i] = c >> 3; acol[i] = (c & 7) << 3;
        int m = m0 + ar[i];
        al[i] = m >> 6; ab[i] = m & 63;
        alen[i] = slen[ab[i]];
    }

    f32x4 zero4 = {0.f,0.f,0.f,0.f};
    f32x4 acc[2][7];
    #pragma unroll
    for (int a=0;a<2;a++)
        #pragma unroll
        for (int g=0;g<7;g++) acc[a][g] = zero4;

    for (int kt=0; kt<25; ++kt){
        __syncthreads();
        if (kt < 20){
            int j = kt >> 2;
            int koff = (kt & 3) << 6;
            #pragma unroll
            for (int i=0;i<4;i++){
                int lp = al[i] + j - 2;
                us8 v = {0,0,0,0,0,0,0,0};
                if ((unsigned)lp < 1024u && lp < alen[i])
                    v = ld8(h0, (size_t)lp*16384 + ab[i]*256 + koff + acol[i], isf);
                *(us8*)(As + ar[i]*LDK + acol[i]) = v;
            }
            #pragma unroll
            for (int i=0;i<4;i++){
                int c = tid + i*256;
                if (c < 896){
                    int rr = c >> 3, col = (c & 7) << 3;
                    int g = rr >> 4, d = d0 + (rr & 15);
                    *(us8*)(Bs + rr*LDK + col) =
                        ld8(Ww, ((size_t)g*256 + d)*1280 + j*256 + koff + col, isf);
                }
            }
        } else {
            int w0 = (kt - 20) << 6;
            #pragma unroll
            for (int i=0;i<16;i++){
                int c = tid + i*256;
                int r = c >> 5, wi = (c & 31) << 1;
                int w = w0 + wi;
                int m = m0 + r;
                unsigned int v = 0;
                if (w < 300) v = ld2(src, (size_t)m*300 + w, isf);
                *(unsigned int*)(As + r*LDK + wi) = v;
            }
            #pragma unroll
            for (int i=0;i<14;i++){
                int c = tid + i*256;
                int rr = c >> 5, wi = (c & 31) << 1;
                int w = w0 + wi;
                int g = rr >> 4, d = d0 + (rr & 15);
                unsigned int v = 0;
                if (w < 300) v = ld2(Wu, ((size_t)g*256 + d)*300 + w, isf);
                *(unsigned int*)(Bs + rr*LDK + wi) = v;
            }
        }
        __syncthreads();
        #pragma unroll
        for (int ks=0; ks<2; ++ks){
            int k0 = (ks << 5) + (qd << 3);
            bf16x8 a0 = *(const bf16x8*)(As + (wv*32 + lc)*LDK + k0);
            bf16x8 a1 = *(const bf16x8*)(As + (wv*32 + 16 + lc)*LDK + k0);
            #pragma unroll
            for (int g=0; g<7; ++g){
                bf16x8 bg = *(const bf16x8*)(Bs + (g*16 + lc)*LDK + k0);
                acc[0][g] = __builtin_amdgcn_mfma_f32_16x16x32_bf16(a0, bg, acc[0][g], 0,0,0);
                acc[1][g] = __builtin_amdgcn_mfma_f32_16x16x32_bf16(a1, bg, acc[1][g], 0,0,0);
            }
        }
    }

    int d = d0 + lc;
    #pragma unroll
    for (int mt=0; mt<2; ++mt){
        #pragma unroll
        for (int r=0; r<4; ++r){
            int m = m0 + wv*32 + mt*16 + qd*4 + r;
            int l = m >> 6, b = m & 63;
            size_t oi = (size_t)m*256 + d;
            int lenb = slen[b];
            float hw = 0.f, cw = 0.f;
            if (l < lenb){
                const float* hv = hgWvB + (size_t)b*1792 + d;
                float p0 = acc[mt][0][r] + hv[0];
                float p1 = acc[mt][1][r] + hv[256];
                float p2 = acc[mt][2][r] + hv[512];
                float p3 = acc[mt][3][r] + hv[768];
                float p4 = acc[mt][4][r] + hv[1024];
                float p5 = acc[mt][5][r] + hv[1280];
                float p6 = acc[mt][6][r] + hv[1536];
                float e_l = __expf(sigf(p1));
                float e_f = __expf(sigf(p3));
                float e_r = __expf(sigf(p2));
                float e_s = __expf(sigf(p4));
                float e_i = __expf(sigf(p0));
                float S = e_l + e_f + e_r + e_s + e_i;
                float u_ = tanhfast(p6);
                float cl = (l >= 1) ? ldf(c0, oi - 16384, isf) : 0.f;
                float cc = ldf(c0, oi, isf);
                float cr = (l + 1 < lenb) ? ldf(c0, oi + 16384, isf) : 0.f;
                float cg1 = ldf(c0, (size_t)16777216 + b*256 + d, isf);
                cw = (e_l*cl + e_f*cc + e_r*cr + e_s*cg1 + e_i*u_) / S;
                hw = sigf(p5) * tanhfast(cw);
            }
            outh[oi] = hw;
            outc[oi] = cw;
        }
    }
}

extern "C" void kernel_launch(void* const* d_in, const int* in_sizes, int n_in,
                              void* d_out, int out_size, void* d_ws, size_t ws_size,
                              hipStream_t stream)
{
    const void* src = d_in[0];
    const void* h0  = d_in[1];
    const void* c0  = d_in[2];
    const void* Ww  = d_in[3];
    const void* Wu  = d_in[4];
    const void* Wv  = d_in[5];
    const void* Wb  = d_in[6];
    const void* Sw  = d_in[7];
    const void* Su  = d_in[8];
    const void* Sb  = d_in[9];
    const int* slen = (const int*)d_in[10];

    float* outh = (float*)d_out;
    float* outc = outh + (size_t)1025*64*256;

    float* ws    = (float*)d_ws;
    float* numv  = ws;
    float* denv  = ws + 16384;
    float* hhat  = ws + 32768;
    float* fg    = ws + 49152;
    float* og    = ws + 65536;
    float* sg    = ws + 81920;
    float* hgWvB = ws + 98304;            // 64*1792 floats -> ends 212992
    int*   flag  = (int*)(ws + 212992);   // 16 floats reserved

    unsigned short* bfbase = (unsigned short*)(ws + 213024);
    unsigned short* hpad   = bfbase;                       // 1028*16384
    unsigned short* srcpad = bfbase + (size_t)16842752;    // 65536*320
    unsigned short* Wcat   = bfbase + (size_t)37814272;    // 1792*1600
    unsigned short* Subf   = bfbase + (size_t)40681472;    // 256*256
    const size_t NEED = 852096 + (size_t)40747008*2;       // 82,346,112 B

    hipLaunchKernelGGL(k_detect, dim3(1), dim3(256), 0, stream, h0, flag);
    hipMemsetAsync(ws, 0, (size_t)3*16384*sizeof(float), stream);   // numv, denv, hhat

    if (ws_size >= NEED){
        hipLaunchKernelGGL(k_conv_h,  dim3(8,1028), dim3(256), 0, stream, h0, slen, hpad, flag);
        hipLaunchKernelGGL(k_conv_src, dim3(10240), dim3(256), 0, stream, src, srcpad, flag);
        hipLaunchKernelGGL(k_conv_w,   dim3(1400),  dim3(256), 0, stream, Ww, Wu, Wcat, flag);
        hipLaunchKernelGGL(k_conv_su,  dim3(32),    dim3(256), 0, stream, Su, Subf, flag);
        hipLaunchKernelGGL(k_hhat_fast, dim3(64,8), dim3(256), 0, stream, hpad, hhat);
        hipLaunchKernelGGL(k_small, dim3(64), dim3(256), 0, stream, h0, hhat, Sw, Su, Sb,
                           fg, og, sg, flag, 1.0f/1024.0f);
        hipLaunchKernelGGL(k_hgwv, dim3(64,7), dim3(256), 0, stream, h0, Wv, Wb, hgWvB, flag);
        hipLaunchKernelGGL(k_fi_fast, dim3(64,16), dim3(256), 0, stream, hpad, c0, Subf, slen,
                           sg, numv, denv, flag);
        hipLaunchKernelGGL(k_cg, dim3(64), dim3(256), 0, stream, c0, fg, og, numv, denv,
                           outh, outc, flag);
        hipLaunchKernelGGL(k_main_fast, dim3(16,512), dim3(256), 0, stream,
                           hpad, srcpad, Wcat, c0, slen, hgWvB, outh, outc, flag);
    } else {
        hipLaunchKernelGGL(k_hhat, dim3(64), dim3(1024), 0, stream, h0, slen, hhat, flag);
        hipLaunchKernelGGL(k_small, dim3(64), dim3(256), 0, stream, h0, hhat, Sw, Su, Sb,
                           fg, og, sg, flag, 1.0f/1024.0f);
        hipLaunchKernelGGL(k_hgwv, dim3(64,7), dim3(256), 0, stream, h0, Wv, Wb, hgWvB, flag);
        hipLaunchKernelGGL(k_fi, dim3(64,16), dim3(256), 0, stream, h0, c0, Su, slen,
                           sg, numv, denv, flag);
        hipLaunchKernelGGL(k_cg, dim3(64), dim3(256), 0, stream, c0, fg, og, numv, denv,
                           outh, outc, flag);
        hipLaunchKernelGGL(k_main, dim3(512,16), dim3(256), 0, stream,
                           src, h0, c0, Ww, Wu, slen, hgWvB, outh, outc, flag);
    }
}